// Round 14
// baseline (150.470 us; speedup 1.0000x reference)
//
#include <hip/hip_runtime.h>
#include <hip/hip_fp16.h>
#include <float.h>

#define NN   768
#define CC   1024
#define HIDD 256
#define NH1  4
#define TOPK 5
#define XW   (CC+4)           // 1028
#define KP   1056             // padded K (33*32)
#define OUTW (NN+7)           // 775
#define G1W  (NH1*HIDD)       // 1024
#define RH   128

typedef __attribute__((ext_vector_type(8))) short short8;
typedef __attribute__((ext_vector_type(4))) float f32x4;

// ---------------- device scratch ---------------------------------------------
__device__ unsigned short g_featsb[NN*CC];     // bf16 feats
__device__ unsigned short g_xb[NN*KP];         // bf16 [feats|geom|0pad]
__device__ unsigned short g_wg1t[G1W*KP];      // bf16 Wg1^T  [n][k]
__device__ unsigned short g_w1f1t[HIDD*CC];    // bf16 W1f1^T
__device__ unsigned short g_w1f2t[HIDD*CC];    // bf16 W1f2^T
__device__ unsigned short g_reginb[NN*XW];     // bf16 [h1|geom]
__device__ __half g_fahp[2*NN*HIDD];           // fa f16 split-K planes
__device__ __half g_fbhp[2*NN*HIDD];           // fb f16 split-K planes
__device__ __half2 g_wrel[5*128];              // packed rel weights [c0..3|wr][f-pair]
__device__ __half g_relph[8*NN*NN];            // rel partials per f-eighth (f16)
__device__ float g_hgp[2*NN*G1W];              // hg split-K planes (f32)
__device__ float g_hg[NN*G1W];                 // combined hg (for gat1)
__device__ float g_as1[NN*NH1], g_ad1[NN*NH1];
__device__ int   g_idx[NN*TOPK];
__device__ float g_h2[NN*2], g_as2[NN], g_ad2[NN];

// ---------------- helpers ----------------------------------------------------
__device__ __forceinline__ unsigned short f2bf(float f){
    unsigned int u = __float_as_uint(f);
    unsigned int r = (u + 0x7FFFu + ((u >> 16) & 1u)) >> 16;
    return (unsigned short)r;
}
// ROCm 7.2 lacks __hmax2; emit v_pk_max_f16 directly.
__device__ __forceinline__ __half2 h2max(__half2 a, __half2 b){
    __half2 r;
    asm("v_pk_max_f16 %0, %1, %2" : "=v"(r) : "v"(a), "v"(b));
    return r;
}

// ---------------- weight transpose + bf16 convert (part of prep_all) ----------
__device__ __forceinline__ void tconv(const float* __restrict__ W, int Kin, int N, int Kpad,
                                      unsigned short* __restrict__ O, int k0, int n0,
                                      int tx, int ty, float (*tile)[33]){
    #pragma unroll
    for (int i = 0; i < 4; i++){
        int k = k0 + ty + 8*i;
        tile[ty+8*i][tx] = (k < Kin) ? W[(size_t)k*N + n0 + tx] : 0.f;
    }
    __syncthreads();
    #pragma unroll
    for (int i = 0; i < 4; i++){
        int n = n0 + ty + 8*i;
        O[(size_t)n*Kpad + k0 + tx] = f2bf(tile[tx][ty+8*i]);
    }
}

// blocks [0,384): feats->bf16; [384,387): geom+pad of xb; 387: g_wrel; [388,1956): weights
__global__ void __launch_bounds__(256) k_prep_all(const float* __restrict__ feats,
                                                  const float* __restrict__ boxes,
                                                  const int* __restrict__ ih,
                                                  const int* __restrict__ iw,
                                                  const float* __restrict__ Wg1,
                                                  const float* __restrict__ W1f1,
                                                  const float* __restrict__ W1f2,
                                                  const float* __restrict__ W1g,
                                                  const float* __restrict__ W2r){
    __shared__ float tile[32][33];
    int b = blockIdx.x, t = threadIdx.x;
    if (b < 384){
        int idx = b*256 + t;                  // 8 elements each, exact cover
        int n = idx >> 7, c8 = (idx & 127) << 3;
        const float* src = &feats[(size_t)n*CC + c8];
        float4 v0 = *(const float4*)src;
        float4 v1 = *(const float4*)(src + 4);
        uint4 pk;
        pk.x = (unsigned)f2bf(v0.x) | ((unsigned)f2bf(v0.y) << 16);
        pk.y = (unsigned)f2bf(v0.z) | ((unsigned)f2bf(v0.w) << 16);
        pk.z = (unsigned)f2bf(v1.x) | ((unsigned)f2bf(v1.y) << 16);
        pk.w = (unsigned)f2bf(v1.z) | ((unsigned)f2bf(v1.w) << 16);
        *(uint4*)&g_featsb[(size_t)n*CC + c8] = pk;
        *(uint4*)&g_xb[(size_t)n*KP + c8] = pk;
        return;
    }
    if (b < 387){
        int n = (b - 384)*256 + t;            // 0..767
        float w = (float)iw[0], h = (float)ih[0];
        float x0 = boxes[n*4+0]/w, y0 = boxes[n*4+1]/h;
        float x1 = boxes[n*4+2]/w, y1 = boxes[n*4+3]/h;
        float ge[4] = {x0, y0, x1-x0, y1-y0};
        #pragma unroll
        for (int c = 0; c < 4; c++)
            g_xb[(size_t)n*KP + CC + c] = f2bf(ge[c]);
        for (int c = 4; c < KP - CC; c++)
            g_xb[(size_t)n*KP + CC + c] = 0;
        return;
    }
    if (b == 387){
        for (int e = t; e < 5*128; e += 256){
            int r = e >> 7, fp = e & 127;
            const float* src = (r < 4) ? &W1g[r*HIDD + 2*fp] : &W2r[2*fp];
            g_wrel[e] = __floats2half2_rn(src[0], src[1]);
        }
        return;
    }
    int bb = b - 388;
    int tx = t & 31, ty = t >> 5;
    if (bb < 1056){                       // Wg1: 1028x1024 -> [1024][1056]
        int kt = bb % 33, nt = bb / 33;
        tconv(Wg1, XW, G1W, KP, g_wg1t, kt*32, nt*32, tx, ty, tile);
    } else if (bb < 1312){                // W1f1: 1024x256 -> [256][1024]
        int b2 = bb - 1056;
        tconv(W1f1, CC, HIDD, CC, g_w1f1t, (b2%32)*32, (b2/32)*32, tx, ty, tile);
    } else {                              // W1f2
        int b2 = bb - 1312;
        tconv(W1f2, CC, HIDD, CC, g_w1f2t, (b2%32)*32, (b2/32)*32, tx, ty, tile);
    }
}

// ---------------- MFMA bf16 GEMM: 64x64 tile, 4 waves, 32x32/wave ------------
#define LSTR 40
__device__ __forceinline__ void mfma_gemm64(const unsigned short* __restrict__ A, int lda,
                                            const unsigned short* __restrict__ Bt, int ldb,
                                            int kstart, int Ks, float* __restrict__ Cf,
                                            __half* __restrict__ Ch, int ldc,
                                            const float* __restrict__ bias, bool relu,
                                            int bm, int bn,
                                            unsigned short* As, unsigned short* Bs){
    const int t = threadIdx.x;
    const int l = t & 63, w = t >> 6;
    const int wr = w >> 1, wc = w & 1;
    const int sr = t >> 2, sq = (t & 3) * 8;
    const size_t aoff = (size_t)(bm + sr)*lda + sq + (size_t)kstart*32;
    const size_t boff = (size_t)(bn + sr)*ldb + sq + (size_t)kstart*32;

    f32x4 acc[2][2];
    #pragma unroll
    for (int i = 0; i < 2; i++)
        #pragma unroll
        for (int j = 0; j < 2; j++)
            acc[i][j] = (f32x4){0.f,0.f,0.f,0.f};

    const int arow0 = (wr*32 + (l & 15)) * LSTR + ((l >> 4) * 8);
    const int brow0 = (wc*32 + (l & 15)) * LSTR + ((l >> 4) * 8);

    float4 a0v, b0v, a1v, b1v;
    a0v = *(const float4*)&A[aoff];            b0v = *(const float4*)&Bt[boff];
    a1v = *(const float4*)&A[aoff + 32];       b1v = *(const float4*)&Bt[boff + 32];

    for (int s = 0; s < Ks; s += 2){
        *(float4*)&As[sr*LSTR + sq] = a0v;
        *(float4*)&Bs[sr*LSTR + sq] = b0v;
        if (s + 2 < Ks){
            a0v = *(const float4*)&A[aoff + (size_t)(s+2)*32];
            b0v = *(const float4*)&Bt[boff + (size_t)(s+2)*32];
        }
        __syncthreads();
        {
            short8 fa0 = *(const short8*)&As[arow0];
            short8 fa1 = *(const short8*)&As[arow0 + 16*LSTR];
            short8 fb0 = *(const short8*)&Bs[brow0];
            short8 fb1 = *(const short8*)&Bs[brow0 + 16*LSTR];
            acc[0][0] = __builtin_amdgcn_mfma_f32_16x16x32_bf16(fa0, fb0, acc[0][0], 0, 0, 0);
            acc[0][1] = __builtin_amdgcn_mfma_f32_16x16x32_bf16(fa0, fb1, acc[0][1], 0, 0, 0);
            acc[1][0] = __builtin_amdgcn_mfma_f32_16x16x32_bf16(fa1, fb0, acc[1][0], 0, 0, 0);
            acc[1][1] = __builtin_amdgcn_mfma_f32_16x16x32_bf16(fa1, fb1, acc[1][1], 0, 0, 0);
        }
        __syncthreads();
        if (s + 1 >= Ks) break;
        *(float4*)&As[64*LSTR + sr*LSTR + sq] = a1v;
        *(float4*)&Bs[64*LSTR + sr*LSTR + sq] = b1v;
        if (s + 3 < Ks){
            a1v = *(const float4*)&A[aoff + (size_t)(s+3)*32];
            b1v = *(const float4*)&Bt[boff + (size_t)(s+3)*32];
        }
        __syncthreads();
        {
            short8 fa0 = *(const short8*)&As[64*LSTR + arow0];
            short8 fa1 = *(const short8*)&As[64*LSTR + arow0 + 16*LSTR];
            short8 fb0 = *(const short8*)&Bs[64*LSTR + brow0];
            short8 fb1 = *(const short8*)&Bs[64*LSTR + brow0 + 16*LSTR];
            acc[0][0] = __builtin_amdgcn_mfma_f32_16x16x32_bf16(fa0, fb0, acc[0][0], 0, 0, 0);
            acc[0][1] = __builtin_amdgcn_mfma_f32_16x16x32_bf16(fa0, fb1, acc[0][1], 0, 0, 0);
            acc[1][0] = __builtin_amdgcn_mfma_f32_16x16x32_bf16(fa1, fb0, acc[1][0], 0, 0, 0);
            acc[1][1] = __builtin_amdgcn_mfma_f32_16x16x32_bf16(fa1, fb1, acc[1][1], 0, 0, 0);
        }
        __syncthreads();
    }

    #pragma unroll
    for (int mi = 0; mi < 2; mi++){
        #pragma unroll
        for (int nj = 0; nj < 2; nj++){
            int col  = bn + wc*32 + nj*16 + (l & 15);
            int row0 = bm + wr*32 + mi*16 + ((l >> 4) * 4);
            float bv = bias ? bias[col] : 0.f;
            #pragma unroll
            for (int r = 0; r < 4; r++){
                float v = acc[mi][nj][r] + bv;
                if (relu) v = fmaxf(v, 0.f);
                if (Ch) Ch[(size_t)(row0+r)*ldc + col] = __float2half(v);
                else    Cf[(size_t)(row0+r)*ldc + col] = v;
            }
        }
    }
}

// split-K x2: blocks [0,384) hg planes, [384,480) fa, [480,576) fb
__global__ void __launch_bounds__(256) k_gemm_all(const float* __restrict__ b1){
    __shared__ unsigned short As[2*64*LSTR];
    __shared__ unsigned short Bs[2*64*LSTR];
    int b = blockIdx.x;
    if (b < 384){
        int p = (b >= 192) ? 1 : 0;
        int bb = b - p*192;
        int ks = p ? 17 : 0, Ks = p ? 16 : 17;   // 33 steps total
        mfma_gemm64(g_xb, KP, g_wg1t, KP, ks, Ks,
                    g_hgp + (size_t)p*NN*G1W, nullptr, G1W, nullptr, false,
                    (bb>>4)*64, (bb&15)*64, As, Bs);
    } else if (b < 480){
        int q = b - 384;
        int p = (q >= 48) ? 1 : 0;
        int bb = q - p*48;
        mfma_gemm64(g_featsb, CC, g_w1f1t, CC, p*16, 16,
                    nullptr, g_fahp + (size_t)p*NN*HIDD, HIDD,
                    p ? nullptr : b1, false,
                    (bb>>2)*64, (bb&3)*64, As, Bs);
    } else {
        int q = b - 480;
        int p = (q >= 48) ? 1 : 0;
        int bb = q - p*48;
        mfma_gemm64(g_featsb, CC, g_w1f2t, CC, p*16, 16,
                    nullptr, g_fbhp + (size_t)p*NN*HIDD, HIDD, nullptr, false,
                    (bb>>2)*64, (bb&3)*64, As, Bs);
    }
}

// ---------------- rel matrix: pk-f16, 2-plane fa/fb combine on stage ---------
#define RSUB 32
__global__ void __launch_bounds__(256) __attribute__((amdgpu_waves_per_eu(4, 4)))
k_rel(const float* __restrict__ boxes){
    __shared__ __half2 sfa[16][68];    // [f-pair][node]
    __shared__ __half2 sfb[16][68];
    const int t = threadIdx.x;
    const int ib = blockIdx.y*64, jb = blockIdx.x*64;
    const int fc0 = blockIdx.z*RSUB;
    const int fpbase = blockIdx.z*16;
    const int rg = t >> 4, cg = t & 15;

    {   // stage: thread (nq,fp) covers nodes nq*4..+3; sum the two split-K planes
        const int fp = t & 15, nq = t >> 4;
        #pragma unroll
        for (int a2 = 0; a2 < 4; a2++){
            int node = nq*4 + a2;
            size_t o = (size_t)(ib+node)*HIDD + fc0 + 2*fp;
            size_t o2 = (size_t)(jb+node)*HIDD + fc0 + 2*fp;
            sfa[fp][node] = __hadd2(*(const __half2*)&g_fahp[o],
                                    *(const __half2*)&g_fahp[o + (size_t)NN*HIDD]);
            sfb[fp][node] = __hadd2(*(const __half2*)&g_fbhp[o2],
                                    *(const __half2*)&g_fbhp[o2 + (size_t)NN*HIDD]);
        }
    }

    // gg from global boxes (12KB, L1-resident)
    float4 bi[4], bj[4];
    #pragma unroll
    for (int a = 0; a < 4; a++) bi[a] = *(const float4*)&boxes[(ib + rg*4 + a)*4];
    #pragma unroll
    for (int b = 0; b < 4; b++) bj[b] = *(const float4*)&boxes[(jb + cg*4 + b)*4];
    __half2 gg[4][4][4];
    #pragma unroll
    for (int a = 0; a < 4; a++)
        #pragma unroll
        for (int b = 0; b < 4; b++){
            const float* pa = (const float*)&bi[a];
            const float* pb = (const float*)&bj[b];
            #pragma unroll
            for (int c = 0; c < 4; c++){
                float gv = fabsf(pa[c] - pb[c]);
                gg[a][b][c] = __floats2half2_rn(gv, gv);
            }
        }
    __syncthreads();

    const __half2 hz = __floats2half2_rn(0.f, 0.f);
    __half2 acc2[4][4];
    #pragma unroll
    for (int a = 0; a < 4; a++)
        #pragma unroll
        for (int b = 0; b < 4; b++) acc2[a][b] = hz;

    #pragma unroll 4
    for (int fp = 0; fp < 16; fp++){
        __half2 w0  = g_wrel[0*128 + fpbase + fp];
        __half2 w1  = g_wrel[1*128 + fpbase + fp];
        __half2 w2  = g_wrel[2*128 + fpbase + fp];
        __half2 w3  = g_wrel[3*128 + fpbase + fp];
        __half2 wrv = g_wrel[4*128 + fpbase + fp];
        float4 fa_raw = *(const float4*)&sfa[fp][rg*4];
        float4 fb_raw = *(const float4*)&sfb[fp][cg*4];
        const __half2* FA = (const __half2*)&fa_raw;
        const __half2* FB = (const __half2*)&fb_raw;
        #pragma unroll
        for (int a = 0; a < 4; a++)
            #pragma unroll
            for (int b = 0; b < 4; b++){
                __half2 s = __hadd2(FA[a], FB[b]);
                s = __hfma2(gg[a][b][0], w0, s);
                s = __hfma2(gg[a][b][1], w1, s);
                s = __hfma2(gg[a][b][2], w2, s);
                s = __hfma2(gg[a][b][3], w3, s);
                s = h2max(s, hz);
                acc2[a][b] = __hfma2(s, wrv, acc2[a][b]);
            }
    }

    __half* po = g_relph + (size_t)blockIdx.z*NN*NN + (size_t)ib*NN + jb;
    #pragma unroll
    for (int a = 0; a < 4; a++){
        unsigned short u[4];
        #pragma unroll
        for (int b = 0; b < 4; b++){
            float sum = __low2float(acc2[a][b]) + __high2float(acc2[a][b]);
            u[b] = __half_as_ushort(__float2half(sum));
        }
        uint2 o;
        o.x = (unsigned)u[0] | ((unsigned)u[1] << 16);
        o.y = (unsigned)u[2] | ((unsigned)u[3] << 16);
        *(uint2*)&po[(size_t)(rg*4+a)*NN + cg*4] = o;
    }
}

// ---------------- topk (+hg combine, alpha1, rel partial combine) ------------
__global__ void __launch_bounds__(64) k_topk(const float* __restrict__ asrc,
                                             const float* __restrict__ adst,
                                             const float* __restrict__ b2r,
                                             float* __restrict__ out){
    int i = blockIdx.x, t = threadIdx.x;
    float* row = out + (size_t)i*OUTW;

    // combine hg planes -> g_hg, and alpha1 dots on combined values
    float ss[4] = {0,0,0,0}, sd[4] = {0,0,0,0};
    const float* hp0 = g_hgp + (size_t)i*G1W;
    const float* hp1 = hp0 + (size_t)NN*G1W;
    float* hout = g_hg + (size_t)i*G1W;
    #pragma unroll
    for (int k = 0; k < 16; k++){
        const int h = k >> 2;
        int u = t + 64*k;
        float hv = hp0[u] + hp1[u];
        hout[u] = hv;
        ss[h] += hv * asrc[u];
        sd[h] += hv * adst[u];
    }
    #pragma unroll
    for (int h = 0; h < 4; h++)
        for (int off = 32; off; off >>= 1){
            ss[h] += __shfl_down(ss[h], off);
            sd[h] += __shfl_down(sd[h], off);
        }
    if (t == 0){
        #pragma unroll
        for (int h = 0; h < 4; h++){ g_as1[i*4+h] = ss[h]; g_ad1[i*4+h] = sd[h]; }
    }

    // combine 8 f16 partials + bias; row in registers for selection.
    const __half* p0 = g_relph + (size_t)i*NN;
    float bb = b2r[0];
    float rv[12];
    #pragma unroll
    for (int kk = 0; kk < 6; kk++){
        int j2 = 128*kk + 2*t;
        float sx = bb, sy = bb;
        #pragma unroll
        for (int z = 0; z < 8; z++){
            __half2 hv = *(const __half2*)&p0[(size_t)z*NN*NN + j2];
            sx += __low2float(hv);
            sy += __high2float(hv);
        }
        rv[2*kk]   = sx;
        rv[2*kk+1] = sy;
        row[j2]   = sx;
        row[j2+1] = sy;
    }

    // top-K over register-cached row; j = 128*(kk>>1) + 2t + (kk&1)
    int sel[TOPK];
    for (int k = 0; k < TOPK; k++){
        float bv = -FLT_MAX; int bj = NN;
        #pragma unroll
        for (int kk = 0; kk < 12; kk++){
            int j = 128*(kk >> 1) + 2*t + (kk & 1);
            if (j == i) continue;
            bool used = false;
            #pragma unroll
            for (int u = 0; u < TOPK; u++) if (u < k && sel[u] == j) used = true;
            if (used) continue;
            float v = rv[kk];
            if (v > bv || (v == bv && j < bj)){ bv = v; bj = j; }
        }
        for (int off = 32; off; off >>= 1){
            float v2 = __shfl_down(bv, off);
            int   j2 = __shfl_down(bj, off);
            if (v2 > bv || (v2 == bv && j2 < bj)){ bv = v2; bj = j2; }
        }
        bv = __shfl(bv, 0); bj = __shfl(bj, 0);
        sel[k] = bj;
    }
    if (t < TOPK) g_idx[i*TOPK + t] = sel[t];
}

// ---------------- GAT1 fused: edge-scan + softmax + aggregate + h2 -----------
__global__ void __launch_bounds__(256) k_gat1(const float* __restrict__ bg1,
                                              const float* __restrict__ Wg2,
                                              const float* __restrict__ as2w,
                                              const float* __restrict__ ad2w,
                                              const float* __restrict__ boxes,
                                              const int* __restrict__ ih,
                                              const int* __restrict__ iw){
    __shared__ float sattn[NN*4];
    __shared__ int   sedge[NN];
    __shared__ int   scnt;
    __shared__ float sden[4];
    __shared__ float sp0[4], sp1[4];
    int n = blockIdx.x, t = threadIdx.x;
    int w = t >> 6, l = t & 63;

    if (t == 0){ scnt = 1; sedge[0] = n; }      // self-loop at slot 0
    __syncthreads();
    for (int s = t; s < NN; s += 256){
        if (s == n) continue;
        const int* ip = &g_idx[s*TOPK];
        bool hit = (ip[0]==n) | (ip[1]==n) | (ip[2]==n) | (ip[3]==n) | (ip[4]==n);
        if (hit){ int p = atomicAdd(&scnt, 1); sedge[p] = s; }
    }
    __syncthreads();
    int deg = scnt;

    {   // wave w = head w: exp(e) and sum
        float adn = g_ad1[n*NH1 + w];
        float s = 0.f;
        for (int e = l; e < deg; e += 64){
            int src = sedge[e];
            float ev = g_as1[src*NH1 + w] + adn;
            ev = (ev > 0.f) ? ev : 0.2f*ev;
            float ex = expf(ev);
            sattn[e*4 + w] = ex;
            s += ex;
        }
        for (int off = 32; off; off >>= 1) s += __shfl_down(s, off);
        if (l == 0) sden[w] = s;
    }
    __syncthreads();

    float rd[NH1];
    #pragma unroll
    for (int h = 0; h < NH1; h++) rd[h] = 1.f / sden[h];
    float acc[NH1] = {0.f,0.f,0.f,0.f};
    for (int e = 0; e < deg; e++){
        int src = sedge[e];
        const float* hr = g_hg + (size_t)src*G1W;
        #pragma unroll
        for (int h = 0; h < NH1; h++)
            acc[h] += sattn[e*4 + h] * hr[h*HIDD + t];
    }
    float p0 = 0.f, p1 = 0.f;
    #pragma unroll
    for (int h = 0; h < NH1; h++){
        int c = h*HIDD + t;
        float v = acc[h]*rd[h] + bg1[c];
        v = fmaxf(v, 0.f);
        g_reginb[(size_t)n*XW + c] = f2bf(v);
        p0 += v * Wg2[c*2 + 0];
        p1 += v * Wg2[c*2 + 1];
    }
    for (int off = 32; off; off >>= 1){
        p0 += __shfl_down(p0, off);
        p1 += __shfl_down(p1, off);
    }
    if (l == 0){ sp0[w] = p0; sp1[w] = p1; }
    __syncthreads();
    if (t == 0){
        float h0 = sp0[0]+sp0[1]+sp0[2]+sp0[3];
        float h1 = sp1[0]+sp1[1]+sp1[2]+sp1[3];
        g_h2[n*2+0] = h0; g_h2[n*2+1] = h1;
        g_as2[n] = h0*as2w[0] + h1*as2w[1];
        g_ad2[n] = h0*ad2w[0] + h1*ad2w[1];
    }
    // geom tail of reginb
    if (t < 4){
        float w2 = (float)iw[0], h2v = (float)ih[0];
        float x0 = boxes[n*4+0]/w2, y0 = boxes[n*4+1]/h2v;
        float x1 = boxes[n*4+2]/w2, y1 = boxes[n*4+3]/h2v;
        float ge[4] = {x0, y0, x1-x0, y1-y0};
        g_reginb[(size_t)n*XW + CC + t] = f2bf(ge[t]);
    }
}

// ---------------- tail: edge-scan + GAT2 + r1 GEMM + box head ----------------
__global__ void __launch_bounds__(64) k_tail(const float* __restrict__ bg2,
                                             const float* __restrict__ Wb1,
                                             const float* __restrict__ bb1,
                                             const float* __restrict__ Wb2,
                                             const float* __restrict__ bb2,
                                             const float* __restrict__ boxes,
                                             float* __restrict__ out){
    __shared__ int sedge[NN];
    __shared__ int scnt;
    int n = blockIdx.x, t = threadIdx.x;

    if (t == 0){ scnt = 1; sedge[0] = n; }
    __syncthreads();
    for (int s = t; s < NN; s += 64){
        if (s == n) continue;
        const int* ip = &g_idx[s*TOPK];
        bool hit = (ip[0]==n) | (ip[1]==n) | (ip[2]==n) | (ip[3]==n) | (ip[4]==n);
        if (hit){ int p = atomicAdd(&scnt, 1); sedge[p] = s; }
    }
    __syncthreads();
    int deg = scnt;

    // GAT2
    float adn = g_ad2[n];
    float den = 0.f, l0 = 0.f, l1 = 0.f;
    for (int e = t; e < deg; e += 64){
        int src = sedge[e];
        float ev = g_as2[src] + adn;
        ev = (ev > 0.f) ? ev : 0.2f*ev;
        float ex = expf(ev);
        den += ex;
        l0 += ex * g_h2[src*2+0];
        l1 += ex * g_h2[src*2+1];
    }
    #pragma unroll
    for (int off = 32; off; off >>= 1){
        den += __shfl_xor(den, off);
        l0  += __shfl_xor(l0, off);
        l1  += __shfl_xor(l1, off);
    }

    // r1 GEMM row: lane t computes r[t], r[t+64] over c<1028 (regin uniform, Wb1 coalesced)
    float s0 = 0.f, s1 = 0.f;
    const unsigned int* rp = (const unsigned int*)&g_reginb[(size_t)n*XW];
    for (int cu = 0; cu < XW/2; cu++){
        unsigned int pk = rp[cu];
        float rA = __uint_as_float(pk << 16);
        float rB = __uint_as_float(pk & 0xffff0000u);
        int c = cu*2;
        s0 += rA * Wb1[(size_t)c*RH + t]      + rB * Wb1[(size_t)(c+1)*RH + t];
        s1 += rA * Wb1[(size_t)c*RH + t + 64] + rB * Wb1[(size_t)(c+1)*RH + t + 64];
    }
    float r0 = fmaxf(s0 + bb1[t], 0.f);
    float r1v = fmaxf(s1 + bb1[t+64], 0.f);
    float4 w0v = *(const float4*)&Wb2[t*4];
    float4 w1v = *(const float4*)&Wb2[(t+64)*4];
    float d0 = r0*w0v.x + r1v*w1v.x;
    float d1 = r0*w0v.y + r1v*w1v.y;
    float d2 = r0*w0v.z + r1v*w1v.z;
    float d3 = r0*w0v.w + r1v*w1v.w;
    #pragma unroll
    for (int off = 32; off; off >>= 1){
        d0 += __shfl_xor(d0, off);
        d1 += __shfl_xor(d1, off);
        d2 += __shfl_xor(d2, off);
        d3 += __shfl_xor(d3, off);
    }

    if (t == 0){
        float rdv = 1.f / den;
        float L0 = l0*rdv + bg2[0];
        float L1 = l1*rdv + bg2[1];
        out[(size_t)n*OUTW + NN + 0] = L0;
        out[(size_t)n*OUTW + NN + 1] = L1;
        float m = fmaxf(L0, L1);
        float e0 = expf(L0 - m), e1 = expf(L1 - m);
        out[(size_t)n*OUTW + NN + 6] = e1 / (e0 + e1);

        float dd0 = d0 + bb2[0], dd1 = d1 + bb2[1];
        float dd2 = d2 + bb2[2], dd3 = d3 + bb2[3];
        float px0 = boxes[n*4+0], py0 = boxes[n*4+1];
        float px1 = boxes[n*4+2], py1 = boxes[n*4+3];
        float pw = px1 - px0, ph = py1 - py0;
        float pcx = px0 + 0.5f*pw, pcy = py0 + 0.5f*ph;
        float gcx = dd0*pw + pcx, gcy = dd1*ph + pcy;
        float gw = expf(dd2)*pw,  gh = expf(dd3)*ph;
        out[(size_t)n*OUTW + NN + 2] = gcx - 0.5f*gw;
        out[(size_t)n*OUTW + NN + 3] = gcy - 0.5f*gh;
        out[(size_t)n*OUTW + NN + 4] = gcx + 0.5f*gw;
        out[(size_t)n*OUTW + NN + 5] = gcy + 0.5f*gh;
    }
}

// ---------------- launch -----------------------------------------------------
extern "C" void kernel_launch(void* const* d_in, const int* in_sizes, int n_in,
                              void* d_out, int out_size, void* d_ws, size_t ws_size,
                              hipStream_t stream){
    const float* feats = (const float*)d_in[0];
    const float* boxes = (const float*)d_in[1];
    const int*   ih    = (const int*)  d_in[2];
    const int*   iw    = (const int*)  d_in[3];
    const float* W1f1  = (const float*)d_in[4];
    const float* W1f2  = (const float*)d_in[5];
    const float* W1g   = (const float*)d_in[6];
    const float* b1    = (const float*)d_in[7];
    const float* W2r   = (const float*)d_in[8];
    const float* b2r   = (const float*)d_in[9];
    const float* Wg1   = (const float*)d_in[10];
    const float* asrc1 = (const float*)d_in[11];
    const float* adst1 = (const float*)d_in[12];
    const float* bg1   = (const float*)d_in[13];
    const float* Wg2   = (const float*)d_in[14];
    const float* asrc2 = (const float*)d_in[15];
    const float* adst2 = (const float*)d_in[16];
    const float* bg2   = (const float*)d_in[17];
    const float* Wb1   = (const float*)d_in[18];
    const float* bb1   = (const float*)d_in[19];
    const float* Wb2   = (const float*)d_in[20];
    const float* bb2   = (const float*)d_in[21];
    float* out = (float*)d_out;

    k_prep_all<<<1956, 256, 0, stream>>>(feats, boxes, ih, iw, Wg1, W1f1, W1f2, W1g, W2r);
    k_gemm_all<<<576, 256, 0, stream>>>(b1);
    k_rel<<<dim3(NN/64, NN/64, 8), 256, 0, stream>>>(boxes);
    k_topk<<<NN, 64, 0, stream>>>(asrc1, adst1, b2r, out);
    k_gat1<<<NN, 256, 0, stream>>>(bg1, Wg2, asrc2, adst2, boxes, ih, iw);
    k_tail<<<NN, 64, 0, stream>>>(bg2, Wb1, bb1, Wb2, bb2, boxes, out);
}

// Round 15
// 85.785 us; speedup vs baseline: 1.7540x; 1.7540x over previous
//
#include <hip/hip_runtime.h>
#include <hip/hip_fp16.h>
#include <float.h>

#define NN   768
#define CC   1024
#define HIDD 256
#define NH1  4
#define TOPK 5
#define XW   (CC+4)           // 1028
#define KP   1056             // padded K (33*32)
#define OUTW (NN+7)           // 775
#define G1W  (NH1*HIDD)       // 1024
#define RH   128

typedef __attribute__((ext_vector_type(8))) short short8;
typedef __attribute__((ext_vector_type(4))) float f32x4;

// ---------------- device scratch ---------------------------------------------
__device__ unsigned short g_featsb[NN*CC];     // bf16 feats
__device__ unsigned short g_xb[NN*KP];         // bf16 [feats|geom|0pad]
__device__ unsigned short g_wg1t[G1W*KP];      // bf16 Wg1^T  [n][k]
__device__ unsigned short g_w1f1t[HIDD*CC];    // bf16 W1f1^T
__device__ unsigned short g_w1f2t[HIDD*CC];    // bf16 W1f2^T
__device__ unsigned short g_wb1t[RH*KP];       // bf16 Wb1^T
__device__ unsigned short g_reginb[NN*KP];     // bf16 [h1|geom|0pad]
__device__ __half g_fahp[2*NN*HIDD];           // fa f16 split-K planes
__device__ __half g_fbhp[2*NN*HIDD];           // fb f16 split-K planes
__device__ __half2 g_wrel[5*128];              // packed rel weights [c0..3|wr][f-pair]
__device__ __half g_relph[8*NN*NN];            // rel partials per f-eighth (f16)
__device__ float g_hgp[2*NN*G1W];              // hg split-K planes (f32)
__device__ float g_hg[NN*G1W];                 // combined hg (for gat1)
__device__ float g_as1[NN*NH1], g_ad1[NN*NH1];
__device__ int   g_idx[NN*TOPK];
__device__ float g_h2[NN*2], g_as2[NN], g_ad2[NN];
__device__ float g_r1p[3*NN*RH];               // split-K partials of regin@Wb1

// ---------------- helpers ----------------------------------------------------
__device__ __forceinline__ unsigned short f2bf(float f){
    unsigned int u = __float_as_uint(f);
    unsigned int r = (u + 0x7FFFu + ((u >> 16) & 1u)) >> 16;
    return (unsigned short)r;
}
// ROCm 7.2 lacks __hmax2; emit v_pk_max_f16 directly.
__device__ __forceinline__ __half2 h2max(__half2 a, __half2 b){
    __half2 r;
    asm("v_pk_max_f16 %0, %1, %2" : "=v"(r) : "v"(a), "v"(b));
    return r;
}

// ---------------- weight transpose + bf16 convert (part of prep_all) ----------
__device__ __forceinline__ void tconv(const float* __restrict__ W, int Kin, int N, int Kpad,
                                      unsigned short* __restrict__ O, int k0, int n0,
                                      int tx, int ty, float (*tile)[33]){
    #pragma unroll
    for (int i = 0; i < 4; i++){
        int k = k0 + ty + 8*i;
        tile[ty+8*i][tx] = (k < Kin) ? W[(size_t)k*N + n0 + tx] : 0.f;
    }
    __syncthreads();
    #pragma unroll
    for (int i = 0; i < 4; i++){
        int n = n0 + ty + 8*i;
        O[(size_t)n*Kpad + k0 + tx] = f2bf(tile[tx][ty+8*i]);
    }
}

// blocks [0,384): feats->bf16; [384,387): geom+pad; 387: g_wrel; [388,2088): weights
__global__ void __launch_bounds__(256) k_prep_all(const float* __restrict__ feats,
                                                  const float* __restrict__ boxes,
                                                  const int* __restrict__ ih,
                                                  const int* __restrict__ iw,
                                                  const float* __restrict__ Wg1,
                                                  const float* __restrict__ W1f1,
                                                  const float* __restrict__ W1f2,
                                                  const float* __restrict__ Wb1,
                                                  const float* __restrict__ W1g,
                                                  const float* __restrict__ W2r){
    __shared__ float tile[32][33];
    int b = blockIdx.x, t = threadIdx.x;
    if (b < 384){
        int idx = b*256 + t;                  // 8 elements each, exact cover
        int n = idx >> 7, c8 = (idx & 127) << 3;
        const float* src = &feats[(size_t)n*CC + c8];
        float4 v0 = *(const float4*)src;
        float4 v1 = *(const float4*)(src + 4);
        uint4 pk;
        pk.x = (unsigned)f2bf(v0.x) | ((unsigned)f2bf(v0.y) << 16);
        pk.y = (unsigned)f2bf(v0.z) | ((unsigned)f2bf(v0.w) << 16);
        pk.z = (unsigned)f2bf(v1.x) | ((unsigned)f2bf(v1.y) << 16);
        pk.w = (unsigned)f2bf(v1.z) | ((unsigned)f2bf(v1.w) << 16);
        *(uint4*)&g_featsb[(size_t)n*CC + c8] = pk;
        *(uint4*)&g_xb[(size_t)n*KP + c8] = pk;
        return;
    }
    if (b < 387){
        int n = (b - 384)*256 + t;            // 0..767
        float w = (float)iw[0], h = (float)ih[0];
        float x0 = boxes[n*4+0]/w, y0 = boxes[n*4+1]/h;
        float x1 = boxes[n*4+2]/w, y1 = boxes[n*4+3]/h;
        float ge[4] = {x0, y0, x1-x0, y1-y0};
        #pragma unroll
        for (int c = 0; c < 4; c++){
            unsigned short bv = f2bf(ge[c]);
            g_xb[(size_t)n*KP + CC + c] = bv;
            g_reginb[(size_t)n*KP + CC + c] = bv;
        }
        for (int c = 4; c < KP - CC; c++){
            g_xb[(size_t)n*KP + CC + c] = 0;
            g_reginb[(size_t)n*KP + CC + c] = 0;
        }
        return;
    }
    if (b == 387){
        for (int e = t; e < 5*128; e += 256){
            int r = e >> 7, fp = e & 127;
            const float* src = (r < 4) ? &W1g[r*HIDD + 2*fp] : &W2r[2*fp];
            g_wrel[e] = __floats2half2_rn(src[0], src[1]);
        }
        return;
    }
    int bb = b - 388;
    int tx = t & 31, ty = t >> 5;
    if (bb < 1056){                       // Wg1: 1028x1024 -> [1024][1056]
        int kt = bb % 33, nt = bb / 33;
        tconv(Wg1, XW, G1W, KP, g_wg1t, kt*32, nt*32, tx, ty, tile);
    } else if (bb < 1312){                // W1f1: 1024x256 -> [256][1024]
        int b2 = bb - 1056;
        tconv(W1f1, CC, HIDD, CC, g_w1f1t, (b2%32)*32, (b2/32)*32, tx, ty, tile);
    } else if (bb < 1568){                // W1f2
        int b2 = bb - 1312;
        tconv(W1f2, CC, HIDD, CC, g_w1f2t, (b2%32)*32, (b2/32)*32, tx, ty, tile);
    } else {                              // Wb1: 1028x128 -> [128][1056]
        int b2 = bb - 1568;
        tconv(Wb1, XW, RH, KP, g_wb1t, (b2%33)*32, (b2/33)*32, tx, ty, tile);
    }
}

// ---------------- MFMA bf16 GEMM: 64x64 tile, 4 waves, 32x32/wave ------------
#define LSTR 40
__device__ __forceinline__ void mfma_gemm64(const unsigned short* __restrict__ A, int lda,
                                            const unsigned short* __restrict__ Bt, int ldb,
                                            int kstart, int Ks, float* __restrict__ Cf,
                                            __half* __restrict__ Ch, int ldc,
                                            const float* __restrict__ bias, bool relu,
                                            int bm, int bn,
                                            unsigned short* As, unsigned short* Bs){
    const int t = threadIdx.x;
    const int l = t & 63, w = t >> 6;
    const int wr = w >> 1, wc = w & 1;
    const int sr = t >> 2, sq = (t & 3) * 8;
    const size_t aoff = (size_t)(bm + sr)*lda + sq + (size_t)kstart*32;
    const size_t boff = (size_t)(bn + sr)*ldb + sq + (size_t)kstart*32;

    f32x4 acc[2][2];
    #pragma unroll
    for (int i = 0; i < 2; i++)
        #pragma unroll
        for (int j = 0; j < 2; j++)
            acc[i][j] = (f32x4){0.f,0.f,0.f,0.f};

    const int arow0 = (wr*32 + (l & 15)) * LSTR + ((l >> 4) * 8);
    const int brow0 = (wc*32 + (l & 15)) * LSTR + ((l >> 4) * 8);

    float4 a0v, b0v, a1v, b1v;
    a0v = *(const float4*)&A[aoff];            b0v = *(const float4*)&Bt[boff];
    a1v = *(const float4*)&A[aoff + 32];       b1v = *(const float4*)&Bt[boff + 32];

    for (int s = 0; s < Ks; s += 2){
        *(float4*)&As[sr*LSTR + sq] = a0v;
        *(float4*)&Bs[sr*LSTR + sq] = b0v;
        if (s + 2 < Ks){
            a0v = *(const float4*)&A[aoff + (size_t)(s+2)*32];
            b0v = *(const float4*)&Bt[boff + (size_t)(s+2)*32];
        }
        __syncthreads();
        {
            short8 fa0 = *(const short8*)&As[arow0];
            short8 fa1 = *(const short8*)&As[arow0 + 16*LSTR];
            short8 fb0 = *(const short8*)&Bs[brow0];
            short8 fb1 = *(const short8*)&Bs[brow0 + 16*LSTR];
            acc[0][0] = __builtin_amdgcn_mfma_f32_16x16x32_bf16(fa0, fb0, acc[0][0], 0, 0, 0);
            acc[0][1] = __builtin_amdgcn_mfma_f32_16x16x32_bf16(fa0, fb1, acc[0][1], 0, 0, 0);
            acc[1][0] = __builtin_amdgcn_mfma_f32_16x16x32_bf16(fa1, fb0, acc[1][0], 0, 0, 0);
            acc[1][1] = __builtin_amdgcn_mfma_f32_16x16x32_bf16(fa1, fb1, acc[1][1], 0, 0, 0);
        }
        __syncthreads();
        if (s + 1 >= Ks) break;
        *(float4*)&As[64*LSTR + sr*LSTR + sq] = a1v;
        *(float4*)&Bs[64*LSTR + sr*LSTR + sq] = b1v;
        if (s + 3 < Ks){
            a1v = *(const float4*)&A[aoff + (size_t)(s+3)*32];
            b1v = *(const float4*)&Bt[boff + (size_t)(s+3)*32];
        }
        __syncthreads();
        {
            short8 fa0 = *(const short8*)&As[64*LSTR + arow0];
            short8 fa1 = *(const short8*)&As[64*LSTR + arow0 + 16*LSTR];
            short8 fb0 = *(const short8*)&Bs[64*LSTR + brow0];
            short8 fb1 = *(const short8*)&Bs[64*LSTR + brow0 + 16*LSTR];
            acc[0][0] = __builtin_amdgcn_mfma_f32_16x16x32_bf16(fa0, fb0, acc[0][0], 0, 0, 0);
            acc[0][1] = __builtin_amdgcn_mfma_f32_16x16x32_bf16(fa0, fb1, acc[0][1], 0, 0, 0);
            acc[1][0] = __builtin_amdgcn_mfma_f32_16x16x32_bf16(fa1, fb0, acc[1][0], 0, 0, 0);
            acc[1][1] = __builtin_amdgcn_mfma_f32_16x16x32_bf16(fa1, fb1, acc[1][1], 0, 0, 0);
        }
        __syncthreads();
    }

    #pragma unroll
    for (int mi = 0; mi < 2; mi++){
        #pragma unroll
        for (int nj = 0; nj < 2; nj++){
            int col  = bn + wc*32 + nj*16 + (l & 15);
            int row0 = bm + wr*32 + mi*16 + ((l >> 4) * 4);
            float bv = bias ? bias[col] : 0.f;
            #pragma unroll
            for (int r = 0; r < 4; r++){
                float v = acc[mi][nj][r] + bv;
                if (relu) v = fmaxf(v, 0.f);
                if (Ch) Ch[(size_t)(row0+r)*ldc + col] = __float2half(v);
                else    Cf[(size_t)(row0+r)*ldc + col] = v;
            }
        }
    }
}

// split-K x2: blocks [0,384) hg planes, [384,480) fa, [480,576) fb
__global__ void __launch_bounds__(256) k_gemm_all(const float* __restrict__ b1){
    __shared__ unsigned short As[2*64*LSTR];
    __shared__ unsigned short Bs[2*64*LSTR];
    int b = blockIdx.x;
    if (b < 384){
        int p = (b >= 192) ? 1 : 0;
        int bb = b - p*192;
        int ks = p ? 17 : 0, Ks = p ? 16 : 17;   // 33 steps total
        mfma_gemm64(g_xb, KP, g_wg1t, KP, ks, Ks,
                    g_hgp + (size_t)p*NN*G1W, nullptr, G1W, nullptr, false,
                    (bb>>4)*64, (bb&15)*64, As, Bs);
    } else if (b < 480){
        int q = b - 384;
        int p = (q >= 48) ? 1 : 0;
        int bb = q - p*48;
        mfma_gemm64(g_featsb, CC, g_w1f1t, CC, p*16, 16,
                    nullptr, g_fahp + (size_t)p*NN*HIDD, HIDD,
                    p ? nullptr : b1, false,
                    (bb>>2)*64, (bb&3)*64, As, Bs);
    } else {
        int q = b - 480;
        int p = (q >= 48) ? 1 : 0;
        int bb = q - p*48;
        mfma_gemm64(g_featsb, CC, g_w1f2t, CC, p*16, 16,
                    nullptr, g_fbhp + (size_t)p*NN*HIDD, HIDD, nullptr, false,
                    (bb>>2)*64, (bb&3)*64, As, Bs);
    }
}

// split-K x3: slice s covers K-steps [11s, 11s+11); partials (no bias/relu)
__global__ void __launch_bounds__(256) k_gemm_r1(){
    __shared__ unsigned short As[2*64*LSTR];
    __shared__ unsigned short Bs[2*64*LSTR];
    int b = blockIdx.x;
    int slice = b / 24, bb = b % 24;
    mfma_gemm64(g_reginb, KP, g_wb1t, KP, slice*11, 11,
                g_r1p + (size_t)slice*NN*RH, nullptr, RH, nullptr, false,
                (bb>>1)*64, (bb&1)*64, As, Bs);
}

// ---------------- rel matrix: pk-f16, 2-plane fa/fb combine on stage ---------
#define RSUB 32
__global__ void __launch_bounds__(256) __attribute__((amdgpu_waves_per_eu(4, 4)))
k_rel(const float* __restrict__ boxes){
    __shared__ __half2 sfa[16][68];    // [f-pair][node]
    __shared__ __half2 sfb[16][68];
    const int t = threadIdx.x;
    const int ib = blockIdx.y*64, jb = blockIdx.x*64;
    const int fc0 = blockIdx.z*RSUB;
    const int fpbase = blockIdx.z*16;
    const int rg = t >> 4, cg = t & 15;

    {   // stage: thread (nq,fp) covers nodes nq*4..+3; sum the two split-K planes
        const int fp = t & 15, nq = t >> 4;
        #pragma unroll
        for (int a2 = 0; a2 < 4; a2++){
            int node = nq*4 + a2;
            size_t o = (size_t)(ib+node)*HIDD + fc0 + 2*fp;
            size_t o2 = (size_t)(jb+node)*HIDD + fc0 + 2*fp;
            sfa[fp][node] = __hadd2(*(const __half2*)&g_fahp[o],
                                    *(const __half2*)&g_fahp[o + (size_t)NN*HIDD]);
            sfb[fp][node] = __hadd2(*(const __half2*)&g_fbhp[o2],
                                    *(const __half2*)&g_fbhp[o2 + (size_t)NN*HIDD]);
        }
    }

    // gg from global boxes (12KB, L1-resident)
    float4 bi[4], bj[4];
    #pragma unroll
    for (int a = 0; a < 4; a++) bi[a] = *(const float4*)&boxes[(ib + rg*4 + a)*4];
    #pragma unroll
    for (int b = 0; b < 4; b++) bj[b] = *(const float4*)&boxes[(jb + cg*4 + b)*4];
    __half2 gg[4][4][4];
    #pragma unroll
    for (int a = 0; a < 4; a++)
        #pragma unroll
        for (int b = 0; b < 4; b++){
            const float* pa = (const float*)&bi[a];
            const float* pb = (const float*)&bj[b];
            #pragma unroll
            for (int c = 0; c < 4; c++){
                float gv = fabsf(pa[c] - pb[c]);
                gg[a][b][c] = __floats2half2_rn(gv, gv);
            }
        }
    __syncthreads();

    const __half2 hz = __floats2half2_rn(0.f, 0.f);
    __half2 acc2[4][4];
    #pragma unroll
    for (int a = 0; a < 4; a++)
        #pragma unroll
        for (int b = 0; b < 4; b++) acc2[a][b] = hz;

    #pragma unroll 4
    for (int fp = 0; fp < 16; fp++){
        __half2 w0  = g_wrel[0*128 + fpbase + fp];
        __half2 w1  = g_wrel[1*128 + fpbase + fp];
        __half2 w2  = g_wrel[2*128 + fpbase + fp];
        __half2 w3  = g_wrel[3*128 + fpbase + fp];
        __half2 wrv = g_wrel[4*128 + fpbase + fp];
        float4 fa_raw = *(const float4*)&sfa[fp][rg*4];
        float4 fb_raw = *(const float4*)&sfb[fp][cg*4];
        const __half2* FA = (const __half2*)&fa_raw;
        const __half2* FB = (const __half2*)&fb_raw;
        #pragma unroll
        for (int a = 0; a < 4; a++)
            #pragma unroll
            for (int b = 0; b < 4; b++){
                __half2 s = __hadd2(FA[a], FB[b]);
                s = __hfma2(gg[a][b][0], w0, s);
                s = __hfma2(gg[a][b][1], w1, s);
                s = __hfma2(gg[a][b][2], w2, s);
                s = __hfma2(gg[a][b][3], w3, s);
                s = h2max(s, hz);
                acc2[a][b] = __hfma2(s, wrv, acc2[a][b]);
            }
    }

    __half* po = g_relph + (size_t)blockIdx.z*NN*NN + (size_t)ib*NN + jb;
    #pragma unroll
    for (int a = 0; a < 4; a++){
        unsigned short u[4];
        #pragma unroll
        for (int b = 0; b < 4; b++){
            float sum = __low2float(acc2[a][b]) + __high2float(acc2[a][b]);
            u[b] = __half_as_ushort(__float2half(sum));
        }
        uint2 o;
        o.x = (unsigned)u[0] | ((unsigned)u[1] << 16);
        o.y = (unsigned)u[2] | ((unsigned)u[3] << 16);
        *(uint2*)&po[(size_t)(rg*4+a)*NN + cg*4] = o;
    }
}

// ---------------- topk (+hg combine, alpha1, rel partial combine) ------------
__global__ void __launch_bounds__(64) k_topk(const float* __restrict__ asrc,
                                             const float* __restrict__ adst,
                                             const float* __restrict__ b2r,
                                             float* __restrict__ out){
    int i = blockIdx.x, t = threadIdx.x;
    float* row = out + (size_t)i*OUTW;

    // combine hg planes -> g_hg, and alpha1 dots on combined values
    float ss[4] = {0,0,0,0}, sd[4] = {0,0,0,0};
    const float* hp0 = g_hgp + (size_t)i*G1W;
    const float* hp1 = hp0 + (size_t)NN*G1W;
    float* hout = g_hg + (size_t)i*G1W;
    #pragma unroll
    for (int k = 0; k < 16; k++){
        const int h = k >> 2;
        int u = t + 64*k;
        float hv = hp0[u] + hp1[u];
        hout[u] = hv;
        ss[h] += hv * asrc[u];
        sd[h] += hv * adst[u];
    }
    #pragma unroll
    for (int h = 0; h < 4; h++)
        for (int off = 32; off; off >>= 1){
            ss[h] += __shfl_down(ss[h], off);
            sd[h] += __shfl_down(sd[h], off);
        }
    if (t == 0){
        #pragma unroll
        for (int h = 0; h < 4; h++){ g_as1[i*4+h] = ss[h]; g_ad1[i*4+h] = sd[h]; }
    }

    // combine 8 f16 partials + bias; row in registers for selection.
    const __half* p0 = g_relph + (size_t)i*NN;
    float bb = b2r[0];
    float rv[12];
    #pragma unroll
    for (int kk = 0; kk < 6; kk++){
        int j2 = 128*kk + 2*t;
        float sx = bb, sy = bb;
        #pragma unroll
        for (int z = 0; z < 8; z++){
            __half2 hv = *(const __half2*)&p0[(size_t)z*NN*NN + j2];
            sx += __low2float(hv);
            sy += __high2float(hv);
        }
        rv[2*kk]   = sx;
        rv[2*kk+1] = sy;
        row[j2]   = sx;
        row[j2+1] = sy;
    }

    // top-K over register-cached row; j = 128*(kk>>1) + 2t + (kk&1)
    int sel[TOPK];
    for (int k = 0; k < TOPK; k++){
        float bv = -FLT_MAX; int bj = NN;
        #pragma unroll
        for (int kk = 0; kk < 12; kk++){
            int j = 128*(kk >> 1) + 2*t + (kk & 1);
            if (j == i) continue;
            bool used = false;
            #pragma unroll
            for (int u = 0; u < TOPK; u++) if (u < k && sel[u] == j) used = true;
            if (used) continue;
            float v = rv[kk];
            if (v > bv || (v == bv && j < bj)){ bv = v; bj = j; }
        }
        for (int off = 32; off; off >>= 1){
            float v2 = __shfl_down(bv, off);
            int   j2 = __shfl_down(bj, off);
            if (v2 > bv || (v2 == bv && j2 < bj)){ bv = v2; bj = j2; }
        }
        bv = __shfl(bv, 0); bj = __shfl(bj, 0);
        sel[k] = bj;
    }
    if (t < TOPK) g_idx[i*TOPK + t] = sel[t];
}

// ---------------- GAT1 fused: edge-scan + softmax + aggregate + h2 -----------
__global__ void __launch_bounds__(256) k_gat1(const float* __restrict__ bg1,
                                              const float* __restrict__ Wg2,
                                              const float* __restrict__ as2w,
                                              const float* __restrict__ ad2w){
    __shared__ float sattn[NN*4];
    __shared__ int   sedge[NN];
    __shared__ int   scnt;
    __shared__ float sden[4];
    __shared__ float sp0[4], sp1[4];
    int n = blockIdx.x, t = threadIdx.x;
    int w = t >> 6, l = t & 63;

    if (t == 0){ scnt = 1; sedge[0] = n; }      // self-loop at slot 0
    __syncthreads();
    for (int s = t; s < NN; s += 256){
        if (s == n) continue;
        const int* ip = &g_idx[s*TOPK];
        bool hit = (ip[0]==n) | (ip[1]==n) | (ip[2]==n) | (ip[3]==n) | (ip[4]==n);
        if (hit){ int p = atomicAdd(&scnt, 1); sedge[p] = s; }
    }
    __syncthreads();
    int deg = scnt;

    {   // wave w = head w: exp(e) and sum
        float adn = g_ad1[n*NH1 + w];
        float s = 0.f;
        for (int e = l; e < deg; e += 64){
            int src = sedge[e];
            float ev = g_as1[src*NH1 + w] + adn;
            ev = (ev > 0.f) ? ev : 0.2f*ev;
            float ex = expf(ev);
            sattn[e*4 + w] = ex;
            s += ex;
        }
        for (int off = 32; off; off >>= 1) s += __shfl_down(s, off);
        if (l == 0) sden[w] = s;
    }
    __syncthreads();

    float rd[NH1];
    #pragma unroll
    for (int h = 0; h < NH1; h++) rd[h] = 1.f / sden[h];
    float acc[NH1] = {0.f,0.f,0.f,0.f};
    for (int e = 0; e < deg; e++){
        int src = sedge[e];
        const float* hr = g_hg + (size_t)src*G1W;
        #pragma unroll
        for (int h = 0; h < NH1; h++)
            acc[h] += sattn[e*4 + h] * hr[h*HIDD + t];
    }
    float p0 = 0.f, p1 = 0.f;
    #pragma unroll
    for (int h = 0; h < NH1; h++){
        int c = h*HIDD + t;
        float v = acc[h]*rd[h] + bg1[c];
        v = fmaxf(v, 0.f);
        g_reginb[(size_t)n*KP + c] = f2bf(v);
        p0 += v * Wg2[c*2 + 0];
        p1 += v * Wg2[c*2 + 1];
    }
    for (int off = 32; off; off >>= 1){
        p0 += __shfl_down(p0, off);
        p1 += __shfl_down(p1, off);
    }
    if (l == 0){ sp0[w] = p0; sp1[w] = p1; }
    __syncthreads();
    if (t == 0){
        float h0 = sp0[0]+sp0[1]+sp0[2]+sp0[3];
        float h1 = sp1[0]+sp1[1]+sp1[2]+sp1[3];
        g_h2[n*2+0] = h0; g_h2[n*2+1] = h1;
        g_as2[n] = h0*as2w[0] + h1*as2w[1];
        g_ad2[n] = h0*ad2w[0] + h1*ad2w[1];
    }
}

// ---------------- tail: edge-scan + GAT2 + r1 combine + box head -------------
__global__ void __launch_bounds__(64) k_tail(const float* __restrict__ bg2,
                                             const float* __restrict__ Wb2,
                                             const float* __restrict__ bb1,
                                             const float* __restrict__ bb2,
                                             const float* __restrict__ boxes,
                                             float* __restrict__ out){
    __shared__ int sedge[NN];
    __shared__ int scnt;
    int n = blockIdx.x, t = threadIdx.x;

    if (t == 0){ scnt = 1; sedge[0] = n; }
    __syncthreads();
    for (int s = t; s < NN; s += 64){
        if (s == n) continue;
        const int* ip = &g_idx[s*TOPK];
        bool hit = (ip[0]==n) | (ip[1]==n) | (ip[2]==n) | (ip[3]==n) | (ip[4]==n);
        if (hit){ int p = atomicAdd(&scnt, 1); sedge[p] = s; }
    }
    __syncthreads();
    int deg = scnt;

    // GAT2: lanes cover edges, butterfly-reduce
    float adn = g_ad2[n];
    float den = 0.f, l0 = 0.f, l1 = 0.f;
    for (int e = t; e < deg; e += 64){
        int src = sedge[e];
        float ev = g_as2[src] + adn;
        ev = (ev > 0.f) ? ev : 0.2f*ev;
        float ex = expf(ev);
        den += ex;
        l0 += ex * g_h2[src*2+0];
        l1 += ex * g_h2[src*2+1];
    }
    #pragma unroll
    for (int off = 32; off; off >>= 1){
        den += __shfl_xor(den, off);
        l0  += __shfl_xor(l0, off);
        l1  += __shfl_xor(l1, off);
    }

    // box head: lane k handles r1[k], r1[k+64] (coalesced partial loads)
    float d0 = 0.f, d1 = 0.f, d2 = 0.f, d3 = 0.f;
    const float* q0 = g_r1p + (size_t)n*RH;
    #pragma unroll
    for (int kk = 0; kk < 2; kk++){
        int k = t + 64*kk;
        float r = q0[k] + q0[k + (size_t)NN*RH] + q0[k + 2*(size_t)NN*RH] + bb1[k];
        r = fmaxf(r, 0.f);
        float4 wv = *(const float4*)&Wb2[k*4];
        d0 += r*wv.x; d1 += r*wv.y; d2 += r*wv.z; d3 += r*wv.w;
    }
    #pragma unroll
    for (int off = 32; off; off >>= 1){
        d0 += __shfl_xor(d0, off);
        d1 += __shfl_xor(d1, off);
        d2 += __shfl_xor(d2, off);
        d3 += __shfl_xor(d3, off);
    }

    if (t == 0){
        float rdv = 1.f / den;
        float L0 = l0*rdv + bg2[0];
        float L1 = l1*rdv + bg2[1];
        out[(size_t)n*OUTW + NN + 0] = L0;
        out[(size_t)n*OUTW + NN + 1] = L1;
        float m = fmaxf(L0, L1);
        float e0 = expf(L0 - m), e1 = expf(L1 - m);
        out[(size_t)n*OUTW + NN + 6] = e1 / (e0 + e1);

        float dd0 = d0 + bb2[0], dd1 = d1 + bb2[1];
        float dd2 = d2 + bb2[2], dd3 = d3 + bb2[3];
        float px0 = boxes[n*4+0], py0 = boxes[n*4+1];
        float px1 = boxes[n*4+2], py1 = boxes[n*4+3];
        float pw = px1 - px0, ph = py1 - py0;
        float pcx = px0 + 0.5f*pw, pcy = py0 + 0.5f*ph;
        float gcx = dd0*pw + pcx, gcy = dd1*ph + pcy;
        float gw = expf(dd2)*pw,  gh = expf(dd3)*ph;
        out[(size_t)n*OUTW + NN + 2] = gcx - 0.5f*gw;
        out[(size_t)n*OUTW + NN + 3] = gcy - 0.5f*gh;
        out[(size_t)n*OUTW + NN + 4] = gcx + 0.5f*gw;
        out[(size_t)n*OUTW + NN + 5] = gcy + 0.5f*gh;
    }
}

// ---------------- launch -----------------------------------------------------
extern "C" void kernel_launch(void* const* d_in, const int* in_sizes, int n_in,
                              void* d_out, int out_size, void* d_ws, size_t ws_size,
                              hipStream_t stream){
    const float* feats = (const float*)d_in[0];
    const float* boxes = (const float*)d_in[1];
    const int*   ih    = (const int*)  d_in[2];
    const int*   iw    = (const int*)  d_in[3];
    const float* W1f1  = (const float*)d_in[4];
    const float* W1f2  = (const float*)d_in[5];
    const float* W1g   = (const float*)d_in[6];
    const float* b1    = (const float*)d_in[7];
    const float* W2r   = (const float*)d_in[8];
    const float* b2r   = (const float*)d_in[9];
    const float* Wg1   = (const float*)d_in[10];
    const float* asrc1 = (const float*)d_in[11];
    const float* adst1 = (const float*)d_in[12];
    const float* bg1   = (const float*)d_in[13];
    const float* Wg2   = (const float*)d_in[14];
    const float* asrc2 = (const float*)d_in[15];
    const float* adst2 = (const float*)d_in[16];
    const float* bg2   = (const float*)d_in[17];
    const float* Wb1   = (const float*)d_in[18];
    const float* bb1   = (const float*)d_in[19];
    const float* Wb2   = (const float*)d_in[20];
    const float* bb2   = (const float*)d_in[21];
    float* out = (float*)d_out;

    k_prep_all<<<2088, 256, 0, stream>>>(feats, boxes, ih, iw, Wg1, W1f1, W1f2, Wb1, W1g, W2r);
    k_gemm_all<<<576, 256, 0, stream>>>(b1);
    k_rel<<<dim3(NN/64, NN/64, 8), 256, 0, stream>>>(boxes);
    k_topk<<<NN, 64, 0, stream>>>(asrc1, adst1, b2r, out);
    k_gat1<<<NN, 256, 0, stream>>>(bg1, Wg2, asrc2, adst2);
    k_gemm_r1<<<72, 256, 0, stream>>>();
    k_tail<<<NN, 64, 0, stream>>>(bg2, Wb2, bb1, bb2, boxes, out);
}

// Round 17
// 85.482 us; speedup vs baseline: 1.7603x; 1.0035x over previous
//
#include <hip/hip_runtime.h>
#include <hip/hip_fp16.h>
#include <float.h>

#define NN   768
#define CC   1024
#define HIDD 256
#define NH1  4
#define TOPK 5
#define XW   (CC+4)           // 1028
#define KP   1056             // padded K (33*32)
#define OUTW (NN+7)           // 775
#define G1W  (NH1*HIDD)       // 1024
#define RH   128

typedef __attribute__((ext_vector_type(8))) short short8;
typedef __attribute__((ext_vector_type(4))) float f32x4;

// ---------------- device scratch ---------------------------------------------
__device__ unsigned short g_featsb[NN*CC];     // bf16 feats
__device__ unsigned short g_xb[NN*KP];         // bf16 [feats|geom|0pad]
__device__ unsigned short g_wg1t[G1W*KP];      // bf16 Wg1^T  [n][k]
__device__ unsigned short g_w1f1t[HIDD*CC];    // bf16 W1f1^T
__device__ unsigned short g_w1f2t[HIDD*CC];    // bf16 W1f2^T
__device__ unsigned short g_wb1t[RH*KP];       // bf16 Wb1^T
__device__ unsigned short g_reginb[NN*KP];     // bf16 [h1|geom|0pad]
__device__ __half g_fahp[2*NN*HIDD];           // fa f16 split-K planes
__device__ __half g_fbhp[2*NN*HIDD];           // fb f16 split-K planes
__device__ __half2 g_wrel[5*128];              // packed rel weights [c0..3|wr][f-pair]
__device__ __half g_relph[8*NN*NN];            // rel partials per f-eighth (f16)
__device__ float g_hgp[2*NN*G1W];              // hg split-K planes (f32)
__device__ float g_hg[NN*G1W];                 // combined hg (for gat1)
__device__ float g_as1[NN*NH1], g_ad1[NN*NH1];
__device__ int   g_idx[NN*TOPK];
__device__ float g_h2[NN*2], g_as2[NN], g_ad2[NN];
__device__ float g_r1p[3*NN*RH];               // split-K partials of regin@Wb1

// ---------------- helpers ----------------------------------------------------
__device__ __forceinline__ unsigned short f2bf(float f){
    unsigned int u = __float_as_uint(f);
    unsigned int r = (u + 0x7FFFu + ((u >> 16) & 1u)) >> 16;
    return (unsigned short)r;
}
// ROCm 7.2 lacks __hmax2; emit v_pk_max_f16 directly.
__device__ __forceinline__ __half2 h2max(__half2 a, __half2 b){
    __half2 r;
    asm("v_pk_max_f16 %0, %1, %2" : "=v"(r) : "v"(a), "v"(b));
    return r;
}

// ---------------- weight transpose + bf16 convert (part of prep_all) ----------
__device__ __forceinline__ void tconv(const float* __restrict__ W, int Kin, int N, int Kpad,
                                      unsigned short* __restrict__ O, int k0, int n0,
                                      int tx, int ty, float (*tile)[33]){
    #pragma unroll
    for (int i = 0; i < 4; i++){
        int k = k0 + ty + 8*i;
        tile[ty+8*i][tx] = (k < Kin) ? W[(size_t)k*N + n0 + tx] : 0.f;
    }
    __syncthreads();
    #pragma unroll
    for (int i = 0; i < 4; i++){
        int n = n0 + ty + 8*i;
        O[(size_t)n*Kpad + k0 + tx] = f2bf(tile[tx][ty+8*i]);
    }
}

// blocks [0,384): feats->bf16; [384,387): geom+pad; 387: g_wrel; [388,2088): weights
__global__ void __launch_bounds__(256) k_prep_all(const float* __restrict__ feats,
                                                  const float* __restrict__ boxes,
                                                  const int* __restrict__ ih,
                                                  const int* __restrict__ iw,
                                                  const float* __restrict__ Wg1,
                                                  const float* __restrict__ W1f1,
                                                  const float* __restrict__ W1f2,
                                                  const float* __restrict__ Wb1,
                                                  const float* __restrict__ W1g,
                                                  const float* __restrict__ W2r){
    __shared__ float tile[32][33];
    int b = blockIdx.x, t = threadIdx.x;
    if (b < 384){
        int idx = b*256 + t;                  // 8 elements each, exact cover
        int n = idx >> 7, c8 = (idx & 127) << 3;
        const float* src = &feats[(size_t)n*CC + c8];
        float4 v0 = *(const float4*)src;
        float4 v1 = *(const float4*)(src + 4);
        uint4 pk;
        pk.x = (unsigned)f2bf(v0.x) | ((unsigned)f2bf(v0.y) << 16);
        pk.y = (unsigned)f2bf(v0.z) | ((unsigned)f2bf(v0.w) << 16);
        pk.z = (unsigned)f2bf(v1.x) | ((unsigned)f2bf(v1.y) << 16);
        pk.w = (unsigned)f2bf(v1.z) | ((unsigned)f2bf(v1.w) << 16);
        *(uint4*)&g_featsb[(size_t)n*CC + c8] = pk;
        *(uint4*)&g_xb[(size_t)n*KP + c8] = pk;
        return;
    }
    if (b < 387){
        int n = (b - 384)*256 + t;            // 0..767
        float w = (float)iw[0], h = (float)ih[0];
        float x0 = boxes[n*4+0]/w, y0 = boxes[n*4+1]/h;
        float x1 = boxes[n*4+2]/w, y1 = boxes[n*4+3]/h;
        float ge[4] = {x0, y0, x1-x0, y1-y0};
        #pragma unroll
        for (int c = 0; c < 4; c++){
            unsigned short bv = f2bf(ge[c]);
            g_xb[(size_t)n*KP + CC + c] = bv;
            g_reginb[(size_t)n*KP + CC + c] = bv;
        }
        for (int c = 4; c < KP - CC; c++){
            g_xb[(size_t)n*KP + CC + c] = 0;
            g_reginb[(size_t)n*KP + CC + c] = 0;
        }
        return;
    }
    if (b == 387){
        for (int e = t; e < 5*128; e += 256){
            int r = e >> 7, fp = e & 127;
            const float* src = (r < 4) ? &W1g[r*HIDD + 2*fp] : &W2r[2*fp];
            g_wrel[e] = __floats2half2_rn(src[0], src[1]);
        }
        return;
    }
    int bb = b - 388;
    int tx = t & 31, ty = t >> 5;
    if (bb < 1056){                       // Wg1: 1028x1024 -> [1024][1056]
        int kt = bb % 33, nt = bb / 33;
        tconv(Wg1, XW, G1W, KP, g_wg1t, kt*32, nt*32, tx, ty, tile);
    } else if (bb < 1312){                // W1f1: 1024x256 -> [256][1024]
        int b2 = bb - 1056;
        tconv(W1f1, CC, HIDD, CC, g_w1f1t, (b2%32)*32, (b2/32)*32, tx, ty, tile);
    } else if (bb < 1568){                // W1f2
        int b2 = bb - 1312;
        tconv(W1f2, CC, HIDD, CC, g_w1f2t, (b2%32)*32, (b2/32)*32, tx, ty, tile);
    } else {                              // Wb1: 1028x128 -> [128][1056]
        int b2 = bb - 1568;
        tconv(Wb1, XW, RH, KP, g_wb1t, (b2%33)*32, (b2/33)*32, tx, ty, tile);
    }
}

// ---------------- MFMA bf16 GEMM: 64x64 tile, 4 waves, 32x32/wave ------------
#define LSTR 40
__device__ __forceinline__ void mfma_gemm64(const unsigned short* __restrict__ A, int lda,
                                            const unsigned short* __restrict__ Bt, int ldb,
                                            int kstart, int Ks, float* __restrict__ Cf,
                                            __half* __restrict__ Ch, int ldc,
                                            const float* __restrict__ bias, bool relu,
                                            int bm, int bn,
                                            unsigned short* As, unsigned short* Bs){
    const int t = threadIdx.x;
    const int l = t & 63, w = t >> 6;
    const int wr = w >> 1, wc = w & 1;
    const int sr = t >> 2, sq = (t & 3) * 8;
    const size_t aoff = (size_t)(bm + sr)*lda + sq + (size_t)kstart*32;
    const size_t boff = (size_t)(bn + sr)*ldb + sq + (size_t)kstart*32;

    f32x4 acc[2][2];
    #pragma unroll
    for (int i = 0; i < 2; i++)
        #pragma unroll
        for (int j = 0; j < 2; j++)
            acc[i][j] = (f32x4){0.f,0.f,0.f,0.f};

    const int arow0 = (wr*32 + (l & 15)) * LSTR + ((l >> 4) * 8);
    const int brow0 = (wc*32 + (l & 15)) * LSTR + ((l >> 4) * 8);

    float4 a0v, b0v, a1v, b1v;
    a0v = *(const float4*)&A[aoff];            b0v = *(const float4*)&Bt[boff];
    a1v = *(const float4*)&A[aoff + 32];       b1v = *(const float4*)&Bt[boff + 32];

    for (int s = 0; s < Ks; s += 2){
        *(float4*)&As[sr*LSTR + sq] = a0v;
        *(float4*)&Bs[sr*LSTR + sq] = b0v;
        if (s + 2 < Ks){
            a0v = *(const float4*)&A[aoff + (size_t)(s+2)*32];
            b0v = *(const float4*)&Bt[boff + (size_t)(s+2)*32];
        }
        __syncthreads();
        {
            short8 fa0 = *(const short8*)&As[arow0];
            short8 fa1 = *(const short8*)&As[arow0 + 16*LSTR];
            short8 fb0 = *(const short8*)&Bs[brow0];
            short8 fb1 = *(const short8*)&Bs[brow0 + 16*LSTR];
            acc[0][0] = __builtin_amdgcn_mfma_f32_16x16x32_bf16(fa0, fb0, acc[0][0], 0, 0, 0);
            acc[0][1] = __builtin_amdgcn_mfma_f32_16x16x32_bf16(fa0, fb1, acc[0][1], 0, 0, 0);
            acc[1][0] = __builtin_amdgcn_mfma_f32_16x16x32_bf16(fa1, fb0, acc[1][0], 0, 0, 0);
            acc[1][1] = __builtin_amdgcn_mfma_f32_16x16x32_bf16(fa1, fb1, acc[1][1], 0, 0, 0);
        }
        __syncthreads();
        if (s + 1 >= Ks) break;
        *(float4*)&As[64*LSTR + sr*LSTR + sq] = a1v;
        *(float4*)&Bs[64*LSTR + sr*LSTR + sq] = b1v;
        if (s + 3 < Ks){
            a1v = *(const float4*)&A[aoff + (size_t)(s+3)*32];
            b1v = *(const float4*)&Bt[boff + (size_t)(s+3)*32];
        }
        __syncthreads();
        {
            short8 fa0 = *(const short8*)&As[64*LSTR + arow0];
            short8 fa1 = *(const short8*)&As[64*LSTR + arow0 + 16*LSTR];
            short8 fb0 = *(const short8*)&Bs[64*LSTR + brow0];
            short8 fb1 = *(const short8*)&Bs[64*LSTR + brow0 + 16*LSTR];
            acc[0][0] = __builtin_amdgcn_mfma_f32_16x16x32_bf16(fa0, fb0, acc[0][0], 0, 0, 0);
            acc[0][1] = __builtin_amdgcn_mfma_f32_16x16x32_bf16(fa0, fb1, acc[0][1], 0, 0, 0);
            acc[1][0] = __builtin_amdgcn_mfma_f32_16x16x32_bf16(fa1, fb0, acc[1][0], 0, 0, 0);
            acc[1][1] = __builtin_amdgcn_mfma_f32_16x16x32_bf16(fa1, fb1, acc[1][1], 0, 0, 0);
        }
        __syncthreads();
    }

    #pragma unroll
    for (int mi = 0; mi < 2; mi++){
        #pragma unroll
        for (int nj = 0; nj < 2; nj++){
            int col  = bn + wc*32 + nj*16 + (l & 15);
            int row0 = bm + wr*32 + mi*16 + ((l >> 4) * 4);
            float bv = bias ? bias[col] : 0.f;
            #pragma unroll
            for (int r = 0; r < 4; r++){
                float v = acc[mi][nj][r] + bv;
                if (relu) v = fmaxf(v, 0.f);
                if (Ch) Ch[(size_t)(row0+r)*ldc + col] = __float2half(v);
                else    Cf[(size_t)(row0+r)*ldc + col] = v;
            }
        }
    }
}

// split-K x2: blocks [0,384) hg planes, [384,480) fa, [480,576) fb
__global__ void __launch_bounds__(256) k_gemm_all(const float* __restrict__ b1){
    __shared__ unsigned short As[2*64*LSTR];
    __shared__ unsigned short Bs[2*64*LSTR];
    int b = blockIdx.x;
    if (b < 384){
        int p = (b >= 192) ? 1 : 0;
        int bb = b - p*192;
        int ks = p ? 17 : 0, Ks = p ? 16 : 17;   // 33 steps total
        mfma_gemm64(g_xb, KP, g_wg1t, KP, ks, Ks,
                    g_hgp + (size_t)p*NN*G1W, nullptr, G1W, nullptr, false,
                    (bb>>4)*64, (bb&15)*64, As, Bs);
    } else if (b < 480){
        int q = b - 384;
        int p = (q >= 48) ? 1 : 0;
        int bb = q - p*48;
        mfma_gemm64(g_featsb, CC, g_w1f1t, CC, p*16, 16,
                    nullptr, g_fahp + (size_t)p*NN*HIDD, HIDD,
                    p ? nullptr : b1, false,
                    (bb>>2)*64, (bb&3)*64, As, Bs);
    } else {
        int q = b - 480;
        int p = (q >= 48) ? 1 : 0;
        int bb = q - p*48;
        mfma_gemm64(g_featsb, CC, g_w1f2t, CC, p*16, 16,
                    nullptr, g_fbhp + (size_t)p*NN*HIDD, HIDD, nullptr, false,
                    (bb>>2)*64, (bb&3)*64, As, Bs);
    }
}

// split-K x3: slice s covers K-steps [11s, 11s+11); partials (no bias/relu)
__global__ void __launch_bounds__(256) k_gemm_r1(){
    __shared__ unsigned short As[2*64*LSTR];
    __shared__ unsigned short Bs[2*64*LSTR];
    int b = blockIdx.x;
    int slice = b / 24, bb = b % 24;
    mfma_gemm64(g_reginb, KP, g_wb1t, KP, slice*11, 11,
                g_r1p + (size_t)slice*NN*RH, nullptr, RH, nullptr, false,
                (bb>>1)*64, (bb&1)*64, As, Bs);
}

// ---------------- rel matrix: pk-f16, 2-plane fa/fb combine on stage ---------
#define RSUB 32
__global__ void __launch_bounds__(256) __attribute__((amdgpu_waves_per_eu(4, 4)))
k_rel(const float* __restrict__ boxes){
    __shared__ __half2 sfa[16][68];    // [f-pair][node]
    __shared__ __half2 sfb[16][68];
    const int t = threadIdx.x;
    const int ib = blockIdx.y*64, jb = blockIdx.x*64;
    const int fc0 = blockIdx.z*RSUB;
    const int fpbase = blockIdx.z*16;
    const int rg = t >> 4, cg = t & 15;

    {   // stage: thread (nq,fp) covers nodes nq*4..+3; sum the two split-K planes
        const int fp = t & 15, nq = t >> 4;
        #pragma unroll
        for (int a2 = 0; a2 < 4; a2++){
            int node = nq*4 + a2;
            size_t o = (size_t)(ib+node)*HIDD + fc0 + 2*fp;
            size_t o2 = (size_t)(jb+node)*HIDD + fc0 + 2*fp;
            sfa[fp][node] = __hadd2(*(const __half2*)&g_fahp[o],
                                    *(const __half2*)&g_fahp[o + (size_t)NN*HIDD]);
            sfb[fp][node] = __hadd2(*(const __half2*)&g_fbhp[o2],
                                    *(const __half2*)&g_fbhp[o2 + (size_t)NN*HIDD]);
        }
    }

    // gg from global boxes (12KB, L1-resident)
    float4 bi[4], bj[4];
    #pragma unroll
    for (int a = 0; a < 4; a++) bi[a] = *(const float4*)&boxes[(ib + rg*4 + a)*4];
    #pragma unroll
    for (int b = 0; b < 4; b++) bj[b] = *(const float4*)&boxes[(jb + cg*4 + b)*4];
    __half2 gg[4][4][4];
    #pragma unroll
    for (int a = 0; a < 4; a++)
        #pragma unroll
        for (int b = 0; b < 4; b++){
            const float* pa = (const float*)&bi[a];
            const float* pb = (const float*)&bj[b];
            #pragma unroll
            for (int c = 0; c < 4; c++){
                float gv = fabsf(pa[c] - pb[c]);
                gg[a][b][c] = __floats2half2_rn(gv, gv);
            }
        }
    __syncthreads();

    const __half2 hz = __floats2half2_rn(0.f, 0.f);
    __half2 acc2[4][4];
    #pragma unroll
    for (int a = 0; a < 4; a++)
        #pragma unroll
        for (int b = 0; b < 4; b++) acc2[a][b] = hz;

    #pragma unroll 4
    for (int fp = 0; fp < 16; fp++){
        __half2 w0  = g_wrel[0*128 + fpbase + fp];
        __half2 w1  = g_wrel[1*128 + fpbase + fp];
        __half2 w2  = g_wrel[2*128 + fpbase + fp];
        __half2 w3  = g_wrel[3*128 + fpbase + fp];
        __half2 wrv = g_wrel[4*128 + fpbase + fp];
        float4 fa_raw = *(const float4*)&sfa[fp][rg*4];
        float4 fb_raw = *(const float4*)&sfb[fp][cg*4];
        const __half2* FA = (const __half2*)&fa_raw;
        const __half2* FB = (const __half2*)&fb_raw;
        #pragma unroll
        for (int a = 0; a < 4; a++)
            #pragma unroll
            for (int b = 0; b < 4; b++){
                __half2 s = __hadd2(FA[a], FB[b]);
                s = __hfma2(gg[a][b][0], w0, s);
                s = __hfma2(gg[a][b][1], w1, s);
                s = __hfma2(gg[a][b][2], w2, s);
                s = __hfma2(gg[a][b][3], w3, s);
                s = h2max(s, hz);
                acc2[a][b] = __hfma2(s, wrv, acc2[a][b]);
            }
    }

    __half* po = g_relph + (size_t)blockIdx.z*NN*NN + (size_t)ib*NN + jb;
    #pragma unroll
    for (int a = 0; a < 4; a++){
        unsigned short u[4];
        #pragma unroll
        for (int b = 0; b < 4; b++){
            float sum = __low2float(acc2[a][b]) + __high2float(acc2[a][b]);
            u[b] = __half_as_ushort(__float2half(sum));
        }
        uint2 o;
        o.x = (unsigned)u[0] | ((unsigned)u[1] << 16);
        o.y = (unsigned)u[2] | ((unsigned)u[3] << 16);
        *(uint2*)&po[(size_t)(rg*4+a)*NN + cg*4] = o;
    }
}

// ---------------- topk (+hg combine, alpha1, rel partial combine) ------------
__global__ void __launch_bounds__(64) k_topk(const float* __restrict__ asrc,
                                             const float* __restrict__ adst,
                                             const float* __restrict__ b2r,
                                             float* __restrict__ out){
    int i = blockIdx.x, t = threadIdx.x;
    float* row = out + (size_t)i*OUTW;

    // combine hg planes -> g_hg, and alpha1 dots on combined values
    float ss[4] = {0,0,0,0}, sd[4] = {0,0,0,0};
    const float* hp0 = g_hgp + (size_t)i*G1W;
    const float* hp1 = hp0 + (size_t)NN*G1W;
    float* hout = g_hg + (size_t)i*G1W;
    #pragma unroll
    for (int k = 0; k < 16; k++){
        const int h = k >> 2;
        int u = t + 64*k;
        float hv = hp0[u] + hp1[u];
        hout[u] = hv;
        ss[h] += hv * asrc[u];
        sd[h] += hv * adst[u];
    }
    #pragma unroll
    for (int h = 0; h < 4; h++)
        for (int off = 32; off; off >>= 1){
            ss[h] += __shfl_down(ss[h], off);
            sd[h] += __shfl_down(sd[h], off);
        }
    if (t == 0){
        #pragma unroll
        for (int h = 0; h < 4; h++){ g_as1[i*4+h] = ss[h]; g_ad1[i*4+h] = sd[h]; }
    }

    // combine 8 f16 partials + bias; row in registers for selection.
    const __half* p0 = g_relph + (size_t)i*NN;
    float bb = b2r[0];
    float rv[12];
    #pragma unroll
    for (int kk = 0; kk < 6; kk++){
        int j2 = 128*kk + 2*t;
        float sx = bb, sy = bb;
        #pragma unroll
        for (int z = 0; z < 8; z++){
            __half2 hv = *(const __half2*)&p0[(size_t)z*NN*NN + j2];
            sx += __low2float(hv);
            sy += __high2float(hv);
        }
        rv[2*kk]   = sx;
        rv[2*kk+1] = sy;
        row[j2]   = sx;
        row[j2+1] = sy;
    }

    // top-K over register-cached row; j = 128*(kk>>1) + 2t + (kk&1)
    int sel[TOPK];
    for (int k = 0; k < TOPK; k++){
        float bv = -FLT_MAX; int bj = NN;
        #pragma unroll
        for (int kk = 0; kk < 12; kk++){
            int j = 128*(kk >> 1) + 2*t + (kk & 1);
            if (j == i) continue;
            bool used = false;
            #pragma unroll
            for (int u = 0; u < TOPK; u++) if (u < k && sel[u] == j) used = true;
            if (used) continue;
            float v = rv[kk];
            if (v > bv || (v == bv && j < bj)){ bv = v; bj = j; }
        }
        for (int off = 32; off; off >>= 1){
            float v2 = __shfl_down(bv, off);
            int   j2 = __shfl_down(bj, off);
            if (v2 > bv || (v2 == bv && j2 < bj)){ bv = v2; bj = j2; }
        }
        bv = __shfl(bv, 0); bj = __shfl(bj, 0);
        sel[k] = bj;
    }
    if (t < TOPK) g_idx[i*TOPK + t] = sel[t];
}

// ---------------- GAT1 fused: edge-scan + softmax + aggregate + h2 -----------
__global__ void __launch_bounds__(256) k_gat1(const float* __restrict__ bg1,
                                              const float* __restrict__ Wg2,
                                              const float* __restrict__ as2w,
                                              const float* __restrict__ ad2w){
    __shared__ float sattn[NN*4];
    __shared__ int   sedge[NN];
    __shared__ int   scnt;
    __shared__ float sden[4];
    __shared__ float sp0[4], sp1[4];
    int n = blockIdx.x, t = threadIdx.x;
    int w = t >> 6, l = t & 63;

    if (t == 0){ scnt = 1; sedge[0] = n; }      // self-loop at slot 0
    __syncthreads();
    for (int s = t; s < NN; s += 256){
        if (s == n) continue;
        const int* ip = &g_idx[s*TOPK];
        bool hit = (ip[0]==n) | (ip[1]==n) | (ip[2]==n) | (ip[3]==n) | (ip[4]==n);
        if (hit){ int p = atomicAdd(&scnt, 1); sedge[p] = s; }
    }
    __syncthreads();
    int deg = scnt;

    {   // wave w = head w: exp(e) and sum
        float adn = g_ad1[n*NH1 + w];
        float s = 0.f;
        for (int e = l; e < deg; e += 64){
            int src = sedge[e];
            float ev = g_as1[src*NH1 + w] + adn;
            ev = (ev > 0.f) ? ev : 0.2f*ev;
            float ex = expf(ev);
            sattn[e*4 + w] = ex;
            s += ex;
        }
        for (int off = 32; off; off >>= 1) s += __shfl_down(s, off);
        if (l == 0) sden[w] = s;
    }
    __syncthreads();

    float rd[NH1];
    #pragma unroll
    for (int h = 0; h < NH1; h++) rd[h] = 1.f / sden[h];
    float acc[NH1] = {0.f,0.f,0.f,0.f};
    for (int e = 0; e < deg; e++){
        int src = sedge[e];
        const float* hr = g_hg + (size_t)src*G1W;
        #pragma unroll
        for (int h = 0; h < NH1; h++)
            acc[h] += sattn[e*4 + h] * hr[h*HIDD + t];
    }
    float p0 = 0.f, p1 = 0.f;
    #pragma unroll
    for (int h = 0; h < NH1; h++){
        int c = h*HIDD + t;
        float v = acc[h]*rd[h] + bg1[c];
        v = fmaxf(v, 0.f);
        g_reginb[(size_t)n*KP + c] = f2bf(v);
        p0 += v * Wg2[c*2 + 0];
        p1 += v * Wg2[c*2 + 1];
    }
    for (int off = 32; off; off >>= 1){
        p0 += __shfl_down(p0, off);
        p1 += __shfl_down(p1, off);
    }
    if (l == 0){ sp0[w] = p0; sp1[w] = p1; }
    __syncthreads();
    if (t == 0){
        float h0 = sp0[0]+sp0[1]+sp0[2]+sp0[3];
        float h1 = sp1[0]+sp1[1]+sp1[2]+sp1[3];
        g_h2[n*2+0] = h0; g_h2[n*2+1] = h1;
        g_as2[n] = h0*as2w[0] + h1*as2w[1];
        g_ad2[n] = h0*ad2w[0] + h1*ad2w[1];
    }
}

// ---------------- tail: edge-scan + GAT2 + r1 combine + box head -------------
__global__ void __launch_bounds__(64) k_tail(const float* __restrict__ bg2,
                                             const float* __restrict__ Wb2,
                                             const float* __restrict__ bb1,
                                             const float* __restrict__ bb2,
                                             const float* __restrict__ boxes,
                                             float* __restrict__ out){
    __shared__ int sedge[NN];
    __shared__ int scnt;
    int n = blockIdx.x, t = threadIdx.x;

    if (t == 0){ scnt = 1; sedge[0] = n; }
    __syncthreads();
    for (int s = t; s < NN; s += 64){
        if (s == n) continue;
        const int* ip = &g_idx[s*TOPK];
        bool hit = (ip[0]==n) | (ip[1]==n) | (ip[2]==n) | (ip[3]==n) | (ip[4]==n);
        if (hit){ int p = atomicAdd(&scnt, 1); sedge[p] = s; }
    }
    __syncthreads();
    int deg = scnt;

    // GAT2: lanes cover edges, butterfly-reduce
    float adn = g_ad2[n];
    float den = 0.f, l0 = 0.f, l1 = 0.f;
    for (int e = t; e < deg; e += 64){
        int src = sedge[e];
        float ev = g_as2[src] + adn;
        ev = (ev > 0.f) ? ev : 0.2f*ev;
        float ex = expf(ev);
        den += ex;
        l0 += ex * g_h2[src*2+0];
        l1 += ex * g_h2[src*2+1];
    }
    #pragma unroll
    for (int off = 32; off; off >>= 1){
        den += __shfl_xor(den, off);
        l0  += __shfl_xor(l0, off);
        l1  += __shfl_xor(l1, off);
    }

    // box head: lane k handles r1[k], r1[k+64] (coalesced partial loads)
    float d0 = 0.f, d1 = 0.f, d2 = 0.f, d3 = 0.f;
    const float* q0 = g_r1p + (size_t)n*RH;
    #pragma unroll
    for (int kk = 0; kk < 2; kk++){
        int k = t + 64*kk;
        float r = q0[k] + q0[k + (size_t)NN*RH] + q0[k + 2*(size_t)NN*RH] + bb1[k];
        r = fmaxf(r, 0.f);
        float4 wv = *(const float4*)&Wb2[k*4];
        d0 += r*wv.x; d1 += r*wv.y; d2 += r*wv.z; d3 += r*wv.w;
    }
    #pragma unroll
    for (int off = 32; off; off >>= 1){
        d0 += __shfl_xor(d0, off);
        d1 += __shfl_xor(d1, off);
        d2 += __shfl_xor(d2, off);
        d3 += __shfl_xor(d3, off);
    }

    if (t == 0){
        float rdv = 1.f / den;
        float L0 = l0*rdv + bg2[0];
        float L1 = l1*rdv + bg2[1];
        out[(size_t)n*OUTW + NN + 0] = L0;
        out[(size_t)n*OUTW + NN + 1] = L1;
        float m = fmaxf(L0, L1);
        float e0 = expf(L0 - m), e1 = expf(L1 - m);
        out[(size_t)n*OUTW + NN + 6] = e1 / (e0 + e1);

        float dd0 = d0 + bb2[0], dd1 = d1 + bb2[1];
        float dd2 = d2 + bb2[2], dd3 = d3 + bb2[3];
        float px0 = boxes[n*4+0], py0 = boxes[n*4+1];
        float px1 = boxes[n*4+2], py1 = boxes[n*4+3];
        float pw = px1 - px0, ph = py1 - py0;
        float pcx = px0 + 0.5f*pw, pcy = py0 + 0.5f*ph;
        float gcx = dd0*pw + pcx, gcy = dd1*ph + pcy;
        float gw = expf(dd2)*pw,  gh = expf(dd3)*ph;
        out[(size_t)n*OUTW + NN + 2] = gcx - 0.5f*gw;
        out[(size_t)n*OUTW + NN + 3] = gcy - 0.5f*gh;
        out[(size_t)n*OUTW + NN + 4] = gcx + 0.5f*gw;
        out[(size_t)n*OUTW + NN + 5] = gcy + 0.5f*gh;
    }
}

// ---------------- launch -----------------------------------------------------
extern "C" void kernel_launch(void* const* d_in, const int* in_sizes, int n_in,
                              void* d_out, int out_size, void* d_ws, size_t ws_size,
                              hipStream_t stream){
    const float* feats = (const float*)d_in[0];
    const float* boxes = (const float*)d_in[1];
    const int*   ih    = (const int*)  d_in[2];
    const int*   iw    = (const int*)  d_in[3];
    const float* W1f1  = (const float*)d_in[4];
    const float* W1f2  = (const float*)d_in[5];
    const float* W1g   = (const float*)d_in[6];
    const float* b1    = (const float*)d_in[7];
    const float* W2r   = (const float*)d_in[8];
    const float* b2r   = (const float*)d_in[9];
    const float* Wg1   = (const float*)d_in[10];
    const float* asrc1 = (const float*)d_in[11];
    const float* adst1 = (const float*)d_in[12];
    const float* bg1   = (const float*)d_in[13];
    const float* Wg2   = (const float*)d_in[14];
    const float* asrc2 = (const float*)d_in[15];
    const float* adst2 = (const float*)d_in[16];
    const float* bg2   = (const float*)d_in[17];
    const float* Wb1   = (const float*)d_in[18];
    const float* bb1   = (const float*)d_in[19];
    const float* Wb2   = (const float*)d_in[20];
    const float* bb2   = (const float*)d_in[21];
    float* out = (float*)d_out;

    k_prep_all<<<2088, 256, 0, stream>>>(feats, boxes, ih, iw, Wg1, W1f1, W1f2, Wb1, W1g, W2r);
    k_gemm_all<<<576, 256, 0, stream>>>(b1);
    k_rel<<<dim3(NN/64, NN/64, 8), 256, 0, stream>>>(boxes);
    k_topk<<<NN, 64, 0, stream>>>(asrc1, adst1, b2r, out);
    k_gat1<<<NN, 256, 0, stream>>>(bg1, Wg2, asrc2, adst2);
    k_gemm_r1<<<72, 256, 0, stream>>>();
    k_tail<<<NN, 64, 0, stream>>>(bg2, Wb2, bb1, bb2, boxes, out);
}